// Round 20
// baseline (212.003 us; speedup 1.0000x reference)
//
#include <hip/hip_runtime.h>
#include <hip/hip_cooperative_groups.h>

namespace cg = cooperative_groups;

#define F0 128
#define F1 64
#define F2 32
#define CPB 256    // cols per bucket (bucket = col >> 8; requires N < 65536)
#define EPB 4096   // edges per coarse chunk (nbC = ceil(E/EPB) must be <= 256)

typedef unsigned short ushort_t;
typedef unsigned int uint_t;

__device__ __forceinline__ ushort_t f2bf(float f) {   // f32 -> bf16 RNE
    uint_t u = __float_as_uint(f);
    return (ushort_t)((u + 0x7FFFu + ((u >> 16) & 1u)) >> 16);
}
__device__ __forceinline__ float bflo(uint_t v) { return __uint_as_float(v << 16); }
__device__ __forceinline__ float bfhi(uint_t v) { return __uint_as_float(v & 0xFFFF0000u); }
__device__ __forceinline__ uint_t pack2(float a, float b) {
    return (uint_t)f2bf(a) | ((uint_t)f2bf(b) << 16);
}

// ================= fused CSR build (cooperative, 256 blocks) =================
// Phase A: per-chunk bucket histograms    (block = chunk)
// Phase B: per-bucket scan over chunks    (block = bucket)
// Phase C: coarse partition into buckets  (block = chunk)
// Phase D: per-bucket CSR + erow place    (block = bucket)
__global__ __launch_bounds__(256) void csr_build(const int* __restrict__ row,
                                                 const int* __restrict__ col,
                                                 int* __restrict__ bcnt_chunks,
                                                 int* __restrict__ btot,
                                                 int* __restrict__ ptr,
                                                 float* __restrict__ dinv,
                                                 ushort_t* __restrict__ erow,
                                                 uint_t* __restrict__ ebuf,
                                                 int N, int E, int nbC, int nbuck) {
    cg::grid_group grid = cg::this_grid();
    __shared__ uint_t stage[EPB];   // 16KB (phase C)
    __shared__ int h1[256];         // hist
    __shared__ int h2[256];         // hbase / pref / cursor
    __shared__ int h3[256];         // scan scratch
    __shared__ int seg_sh[2];
    int b = blockIdx.x;
    int t = threadIdx.x;

    // ---- Phase A: count buckets in chunk b ----
    if (b < nbC) {
        h1[t] = 0;
        __syncthreads();
        int e0 = b * EPB;
        int cnt = E - e0; if (cnt > EPB) cnt = EPB;
        for (int k = t; k < cnt; k += 256) atomicAdd(&h1[col[e0 + k] >> 8], 1);
        __syncthreads();
        bcnt_chunks[b * 256 + t] = h1[t];
    }
    grid.sync();

    // ---- Phase B: scan chunks for bucket b; write local prefixes + btot ----
    {
        int v = (t < nbC) ? bcnt_chunks[t * 256 + b] : 0;
        h3[t] = v;
        __syncthreads();
        for (int off = 1; off < 256; off <<= 1) {
            int u = (t >= off) ? h3[t - off] : 0;
            __syncthreads();
            h3[t] += u;
            __syncthreads();
        }
        if (t < nbC) bcnt_chunks[t * 256 + b] = h3[t] - v;
        if (t == 255) btot[b] = h3[255];
    }
    grid.sync();

    // ---- bucket_base exclusive scan (all blocks, kept in register `excl`) ----
    int excl;
    {
        int bv = btot[t];
        h3[t] = bv;
        __syncthreads();
        for (int off = 1; off < 256; off <<= 1) {
            int u = (t >= off) ? h3[t - off] : 0;
            __syncthreads();
            h3[t] += u;
            __syncthreads();
        }
        excl = h3[t] - bv;
    }
    __syncthreads();

    // ---- Phase C: coarse partition of chunk b ----
    if (b < nbC) {
        h2[t] = bcnt_chunks[b * 256 + t] + excl;   // global run start
        h1[t] = 0;
        __syncthreads();
        int e0 = b * EPB;
        int cnt = E - e0; if (cnt > EPB) cnt = EPB;
        for (int k = t; k < cnt; k += 256) {
            int c = col[e0 + k], r = row[e0 + k];
            stage[k] = ((uint_t)r << 16) | (uint_t)c;
        }
        __syncthreads();
        for (int k = t; k < cnt; k += 256) {
            uint_t p = stage[k];
            int bk = (int)((p & 0xFFFFu) >> 8);
            int rk = atomicAdd(&h1[bk], 1);        // local rank (LDS)
            ebuf[h2[bk] + rk] = p;
        }
    }
    grid.sync();

    // ---- Phase D: per-bucket CSR + place erow ----
    {
        if (t == b) seg_sh[0] = excl;
        if (b < 255 && t == b + 1) seg_sh[1] = excl;
        if (b == 255 && t == 0) seg_sh[1] = E;
        h1[t] = 0;
        __syncthreads();
        int seg0 = seg_sh[0];
        int seg1 = seg_sh[1];
        int cbase = b << 8;

        for (int k = seg0 + t; k < seg1; k += 256)
            atomicAdd(&h1[ebuf[k] & 255u], 1);
        __syncthreads();
        int deg = h1[t];
        h2[t] = deg;
        __syncthreads();
        for (int off = 1; off < 256; off <<= 1) {
            int u = (t >= off) ? h2[t - off] : 0;
            __syncthreads();
            h2[t] += u;
            __syncthreads();
        }
        int base = seg0 + h2[t] - deg;
        int c = cbase + t;
        if (c < N) {
            ptr[c] = base;
            dinv[c] = rsqrtf((float)(deg + 1));
        }
        if (b == nbuck - 1 && t == 0) ptr[N] = E;
        __syncthreads();
        h2[t] = base;                               // cursor
        __syncthreads();
        for (int k = seg0 + t; k < seg1; k += 256) {
            uint_t p = ebuf[k];
            int pos = atomicAdd(&h2[p & 255u], 1);
            erow[pos] = (ushort_t)(p >> 16);
        }
    }
}

// ================= register-tiled GEMMs =================
__device__ __forceinline__ void fma4(float4& a, float xs, const float4& wv) {
    a.x = fmaf(xs, wv.x, a.x);
    a.y = fmaf(xs, wv.y, a.y);
    a.z = fmaf(xs, wv.z, a.z);
    a.w = fmaf(xs, wv.w, a.w);
}

// gemm1: xwb = (x @ W1) * dinv[row], stored bf16. tile 64x64, thread = 4x4.
__global__ __launch_bounds__(256) void gemm1(const float* __restrict__ x,
                                             const float* __restrict__ W,
                                             const float* __restrict__ dinv,
                                             ushort_t* __restrict__ xwb, int N) {
    __shared__ float Xl[64 * F0];   // 32KB, swizzled
    __shared__ float Wl[F0 * F1];   // 32KB, linear [k][64]
    int tid = threadIdx.x;
    int base = blockIdx.x * 64;

    const float4* W4 = (const float4*)W;
    float4* Wl4 = (float4*)Wl;
#pragma unroll
    for (int i = 0; i < 8; ++i) Wl4[tid + 256 * i] = W4[tid + 256 * i];

    float4* Xl4 = (float4*)Xl;
#pragma unroll
    for (int i = 0; i < 8; ++i) {
        int idx = tid + 256 * i;
        int r = idx >> 5, c4 = idx & 31;
        int gr = base + r;
        float4 v = (gr < N) ? ((const float4*)x)[(size_t)gr * 32 + c4]
                            : make_float4(0.f, 0.f, 0.f, 0.f);
        Xl4[r * 32 + (c4 ^ (r >> 2))] = v;
    }
    __syncthreads();

    int tc = tid & 15, tr = tid >> 4;
    float4 acc0 = make_float4(0.f, 0.f, 0.f, 0.f);
    float4 acc1 = acc0, acc2 = acc0, acc3 = acc0;
    const float4* Wl4c = (const float4*)Wl;
    const float4* Xl4c = (const float4*)Xl;

#pragma unroll 4
    for (int kk = 0; kk < 32; ++kk) {
        float4 xv0 = Xl4c[(4 * tr + 0) * 32 + (kk ^ tr)];
        float4 xv1 = Xl4c[(4 * tr + 1) * 32 + (kk ^ tr)];
        float4 xv2 = Xl4c[(4 * tr + 2) * 32 + (kk ^ tr)];
        float4 xv3 = Xl4c[(4 * tr + 3) * 32 + (kk ^ tr)];
        float4 w0 = Wl4c[(4 * kk + 0) * 16 + tc];
        float4 w1 = Wl4c[(4 * kk + 1) * 16 + tc];
        float4 w2 = Wl4c[(4 * kk + 2) * 16 + tc];
        float4 w3 = Wl4c[(4 * kk + 3) * 16 + tc];
        fma4(acc0, xv0.x, w0); fma4(acc0, xv0.y, w1); fma4(acc0, xv0.z, w2); fma4(acc0, xv0.w, w3);
        fma4(acc1, xv1.x, w0); fma4(acc1, xv1.y, w1); fma4(acc1, xv1.z, w2); fma4(acc1, xv1.w, w3);
        fma4(acc2, xv2.x, w0); fma4(acc2, xv2.y, w1); fma4(acc2, xv2.z, w2); fma4(acc2, xv2.w, w3);
        fma4(acc3, xv3.x, w0); fma4(acc3, xv3.y, w1); fma4(acc3, xv3.z, w2); fma4(acc3, xv3.w, w3);
    }

    int gr = base + 4 * tr;
#pragma unroll
    for (int k = 0; k < 4; ++k) {
        int r = gr + k;
        if (r < N) {
            float d = dinv[r];
            float4 a = (k == 0) ? acc0 : (k == 1) ? acc1 : (k == 2) ? acc2 : acc3;
            ushort4 o = make_ushort4(f2bf(a.x * d), f2bf(a.y * d), f2bf(a.z * d), f2bf(a.w * d));
            *(ushort4*)(&xwb[(size_t)r * F1 + 4 * tc]) = o;
        }
    }
}

// ================= layer 1 aggregation (r15/r18 structure): wave/node =========
__global__ void agg1(const int* __restrict__ ptr, const ushort_t* __restrict__ erow,
                     const ushort_t* __restrict__ xwb, const float* __restrict__ dinv,
                     const float* __restrict__ b, ushort_t* __restrict__ h1b, int N) {
    int t = blockIdx.x * 256 + threadIdx.x;
    int i = t >> 6;
    if (i >= N) return;
    int l = t & 63, h = l >> 5, l2 = l & 31;
    const uint_t* xwb2 = (const uint_t*)xwb;

    float a0 = 0.f, a1 = 0.f;
    int e = ptr[i], end = ptr[i + 1];
    for (; e + 7 < end; e += 8) {
        int r0 = erow[e + 0 + h], r1 = erow[e + 2 + h];
        int r2 = erow[e + 4 + h], r3 = erow[e + 6 + h];
        uint_t v0 = xwb2[(size_t)r0 * 32 + l2];
        uint_t v1 = xwb2[(size_t)r1 * 32 + l2];
        uint_t v2 = xwb2[(size_t)r2 * 32 + l2];
        uint_t v3 = xwb2[(size_t)r3 * 32 + l2];
        a0 += bflo(v0); a1 += bfhi(v0);
        a0 += bflo(v1); a1 += bfhi(v1);
        a0 += bflo(v2); a1 += bfhi(v2);
        a0 += bflo(v3); a1 += bfhi(v3);
    }
    for (; e + 1 < end; e += 2) {
        int r0 = erow[e + h];
        uint_t v0 = xwb2[(size_t)r0 * 32 + l2];
        a0 += bflo(v0); a1 += bfhi(v0);
    }
    if (e < end && h == 0) {            // odd leftover: half 0 only
        uint_t v0 = xwb2[(size_t)erow[e] * 32 + l2];
        a0 += bflo(v0); a1 += bfhi(v0);
    }
    a0 += __shfl_down(a0, 32, 64);      // merge halves into lanes 0..31
    a1 += __shfl_down(a1, 32, 64);
    if (h == 0) {
        uint_t sv = xwb2[(size_t)i * 32 + l2];    // scaled self term
        a0 += bflo(sv); a1 += bfhi(sv);
        float d = dinv[i];
        float2 bb = ((const float2*)b)[l2];
        a0 = fmaxf(a0 * d + bb.x, 0.f);
        a1 = fmaxf(a1 * d + bb.y, 0.f);
        ((uint_t*)h1b)[(size_t)i * 32 + l2] = pack2(a0, a1);
    }
}

// gemm2: hwb = (h1b @ W2) * dinv[row], bf16 in / bf16 out. tile 128x32, 4x4.
__global__ __launch_bounds__(256) void gemm2(const ushort_t* __restrict__ h1b,
                                             const float* __restrict__ W,
                                             const float* __restrict__ dinv,
                                             ushort_t* __restrict__ hwb, int N) {
    __shared__ float Hl[128 * F1];  // 32KB, swizzled
    __shared__ float Wl[F1 * F2];   // 8KB
    int tid = threadIdx.x;
    int base = blockIdx.x * 128;

    const float4* W4 = (const float4*)W;
    float4* Wl4 = (float4*)Wl;
#pragma unroll
    for (int i = 0; i < 2; ++i) Wl4[tid + 256 * i] = W4[tid + 256 * i];

    const uint4* H4 = (const uint4*)h1b;
    float4* Hl4 = (float4*)Hl;
#pragma unroll
    for (int it = 0; it < 4; ++it) {
        int g = tid + 256 * it;
        int r = g >> 3, c8 = g & 7;
        int gr = base + r;
        uint4 v = (gr < N) ? H4[(size_t)gr * 8 + c8] : make_uint4(0, 0, 0, 0);
        float4 a, b2;
        a.x = bflo(v.x); a.y = bfhi(v.x);
        a.z = bflo(v.y); a.w = bfhi(v.y);
        b2.x = bflo(v.z); b2.y = bfhi(v.z);
        b2.z = bflo(v.w); b2.w = bfhi(v.w);
        int sw = (r >> 2) & 15;
        Hl4[r * 16 + ((2 * c8 + 0) ^ sw)] = a;
        Hl4[r * 16 + ((2 * c8 + 1) ^ sw)] = b2;
    }
    __syncthreads();

    int tc = tid & 7, tr = tid >> 3;
    float4 acc0 = make_float4(0.f, 0.f, 0.f, 0.f);
    float4 acc1 = acc0, acc2 = acc0, acc3 = acc0;
    const float4* Wl4c = (const float4*)Wl;
    const float4* Hl4c = (const float4*)Hl;

#pragma unroll 4
    for (int kk = 0; kk < 16; ++kk) {
        int sw = kk ^ (tr & 15);
        float4 xv0 = Hl4c[(4 * tr + 0) * 16 + sw];
        float4 xv1 = Hl4c[(4 * tr + 1) * 16 + sw];
        float4 xv2 = Hl4c[(4 * tr + 2) * 16 + sw];
        float4 xv3 = Hl4c[(4 * tr + 3) * 16 + sw];
        float4 w0 = Wl4c[(4 * kk + 0) * 8 + tc];
        float4 w1 = Wl4c[(4 * kk + 1) * 8 + tc];
        float4 w2 = Wl4c[(4 * kk + 2) * 8 + tc];
        float4 w3 = Wl4c[(4 * kk + 3) * 8 + tc];
        fma4(acc0, xv0.x, w0); fma4(acc0, xv0.y, w1); fma4(acc0, xv0.z, w2); fma4(acc0, xv0.w, w3);
        fma4(acc1, xv1.x, w0); fma4(acc1, xv1.y, w1); fma4(acc1, xv1.z, w2); fma4(acc1, xv1.w, w3);
        fma4(acc2, xv2.x, w0); fma4(acc2, xv2.y, w1); fma4(acc2, xv2.z, w2); fma4(acc2, xv2.w, w3);
        fma4(acc3, xv3.x, w0); fma4(acc3, xv3.y, w1); fma4(acc3, xv3.z, w2); fma4(acc3, xv3.w, w3);
    }

    int gr = base + 4 * tr;
#pragma unroll
    for (int k = 0; k < 4; ++k) {
        int r = gr + k;
        if (r < N) {
            float d = dinv[r];
            float4 a = (k == 0) ? acc0 : (k == 1) ? acc1 : (k == 2) ? acc2 : acc3;
            ushort4 o = make_ushort4(f2bf(a.x * d), f2bf(a.y * d), f2bf(a.z * d), f2bf(a.w * d));
            *(ushort4*)(&hwb[(size_t)r * F2 + 4 * tc]) = o;
        }
    }
}

// ================= layer 2 aggregation + fused log_softmax (r15/r18) =========
__global__ void agg2_lsm(const int* __restrict__ ptr, const ushort_t* __restrict__ erow,
                         const ushort_t* __restrict__ hwb, const float* __restrict__ dinv,
                         const float* __restrict__ b, float* __restrict__ out, int N) {
    int t = blockIdx.x * 256 + threadIdx.x;
    int i = t >> 5;
    if (i >= N) return;
    int g = t & 31, h = g >> 4, l2 = g & 15;
    const uint_t* hwb2 = (const uint_t*)hwb;

    float a0 = 0.f, a1 = 0.f;
    int e = ptr[i], end = ptr[i + 1];
    for (; e + 7 < end; e += 8) {
        int r0 = erow[e + 0 + h], r1 = erow[e + 2 + h];
        int r2 = erow[e + 4 + h], r3 = erow[e + 6 + h];
        uint_t v0 = hwb2[(size_t)r0 * 16 + l2];
        uint_t v1 = hwb2[(size_t)r1 * 16 + l2];
        uint_t v2 = hwb2[(size_t)r2 * 16 + l2];
        uint_t v3 = hwb2[(size_t)r3 * 16 + l2];
        a0 += bflo(v0); a1 += bfhi(v0);
        a0 += bflo(v1); a1 += bfhi(v1);
        a0 += bflo(v2); a1 += bfhi(v2);
        a0 += bflo(v3); a1 += bfhi(v3);
    }
    for (; e + 1 < end; e += 2) {
        int r0 = erow[e + h];
        uint_t v0 = hwb2[(size_t)r0 * 16 + l2];
        a0 += bflo(v0); a1 += bfhi(v0);
    }
    if (e < end && h == 0) {
        uint_t v0 = hwb2[(size_t)erow[e] * 16 + l2];
        a0 += bflo(v0); a1 += bfhi(v0);
    }
    a0 += __shfl_down(a0, 16, 32);     // merge slots into lanes (g<16)
    a1 += __shfl_down(a1, 16, 32);

    uint_t sv = hwb2[(size_t)i * 16 + l2];
    a0 += bflo(sv); a1 += bfhi(sv);
    float d = dinv[i];
    float2 bb = ((const float2*)b)[l2];
    a0 = a0 * d + bb.x;
    a1 = a1 * d + bb.y;

    float m = fmaxf(a0, a1);
    for (int off = 8; off; off >>= 1) m = fmaxf(m, __shfl_xor(m, off, 16));
    float s = expf(a0 - m) + expf(a1 - m);
    for (int off = 8; off; off >>= 1) s += __shfl_xor(s, off, 16);
    float ls = logf(s);
    if (h == 0)
        ((float2*)out)[(size_t)i * 16 + l2] = make_float2(a0 - m - ls, a1 - m - ls);
}

extern "C" void kernel_launch(void* const* d_in, const int* in_sizes, int n_in,
                              void* d_out, int out_size, void* d_ws, size_t ws_size,
                              hipStream_t stream) {
    const float* x  = (const float*)d_in[0];
    const int*   ei = (const int*)d_in[1];
    const float* W1 = (const float*)d_in[2];
    const float* b1 = (const float*)d_in[3];
    const float* W2 = (const float*)d_in[4];
    const float* b2 = (const float*)d_in[5];

    int N = in_sizes[0] / F0;
    int E = in_sizes[1] / 2;
    const int* row = ei;
    const int* col = ei + E;

    int nbC   = (E + EPB - 1) / EPB;          // edge chunks (<= 256)
    int nbuck = (N + CPB - 1) / CPB;          // buckets (<= 256)

    size_t Np = ((size_t)N + 63) & ~(size_t)63;
    size_t Ep = ((size_t)E + 63) & ~(size_t)63;
    size_t Cp = (((size_t)nbC * 256) + 63) & ~(size_t)63;
    int*      bcnt_chunks = (int*)d_ws;                  // nbC*256
    int*      btot        = bcnt_chunks + Cp;            // 256
    int*      ptr         = btot + 256 + 64;             // Np+64
    float*    dinv        = (float*)(ptr + Np + 64);     // Np
    ushort_t* erow        = (ushort_t*)(dinv + Np);      // Ep ushorts
    uint_t*   ebuf        = (uint_t*)(erow + Ep);        // Ep packed edges
    ushort_t* xwb         = (ushort_t*)(ebuf + Ep);      // Np*64 bf16
    ushort_t* h1b         = xwb + Np * F1;               // Np*64 bf16
    ushort_t* hwb         = h1b + Np * F1;               // Np*32 bf16
    float*    out2        = (float*)d_out;

    void* args[] = {(void*)&row, (void*)&col, (void*)&bcnt_chunks, (void*)&btot,
                    (void*)&ptr, (void*)&dinv, (void*)&erow, (void*)&ebuf,
                    (void*)&N, (void*)&E, (void*)&nbC, (void*)&nbuck};
    hipLaunchCooperativeKernel((void*)csr_build, dim3(256), dim3(256), args, 0, stream);

    gemm1<<<(N + 63) / 64, 256, 0, stream>>>(x, W1, dinv, xwb, N);
    agg1<<<(int)(((size_t)N * 64 + 255) / 256), 256, 0, stream>>>(ptr, erow, xwb, dinv, b1, h1b, N);
    gemm2<<<(N + 127) / 128, 256, 0, stream>>>(h1b, W2, dinv, hwb, N);
    agg2_lsm<<<(int)(((size_t)N * 32 + 255) / 256), 256, 0, stream>>>(ptr, erow, hwb, dinv, b2, out2, N);
}

// Round 21
// 111.242 us; speedup vs baseline: 1.9058x; 1.9058x over previous
//
#include <hip/hip_runtime.h>

#define F0 128
#define F1 64
#define F2 32
#define CPB 256    // cols per bucket (bucket = col >> 8; requires N < 65536)
#define EPB 4096   // edges per coarse block (nbC = ceil(E/EPB) must be <= 256)

typedef unsigned short ushort_t;
typedef unsigned int uint_t;

__device__ __forceinline__ ushort_t f2bf(float f) {   // f32 -> bf16 RNE
    uint_t u = __float_as_uint(f);
    return (ushort_t)((u + 0x7FFFu + ((u >> 16) & 1u)) >> 16);
}
__device__ __forceinline__ float bflo(uint_t v) { return __uint_as_float(v << 16); }
__device__ __forceinline__ float bfhi(uint_t v) { return __uint_as_float(v & 0xFFFF0000u); }
__device__ __forceinline__ uint_t pack2(float a, float b) {
    return (uint_t)f2bf(a) | ((uint_t)f2bf(b) << 16);
}

// ================= CSR build (bucket-level front-end) =================
// per-chunk bucket counts, written non-atomically (no zeroing pass needed)
__global__ __launch_bounds__(256) void bucket_count(const int* __restrict__ col,
                                                    int* __restrict__ bcnt_chunks, int E) {
    __shared__ int h[256];
    int t = threadIdx.x;
    h[t] = 0;
    __syncthreads();
    int e0 = blockIdx.x * EPB;
    int cnt = E - e0; if (cnt > EPB) cnt = EPB;
    for (int k = t; k < cnt; k += 256) atomicAdd(&h[col[e0 + k] >> 8], 1);
    __syncthreads();
    bcnt_chunks[blockIdx.x * 256 + t] = h[t];
}

// 256 blocks, one per bucket b: parallel scan of h[c][b] over chunks c.
// Rewrites bcnt_chunks[c][b] as the within-bucket exclusive prefix; btot[b]=total.
__global__ __launch_bounds__(256) void per_bucket_scan(int* __restrict__ bcnt_chunks,
                                                       int nbC, int* __restrict__ btot) {
    __shared__ int s[256];
    int b = blockIdx.x;
    int t = threadIdx.x;
    int v = (t < nbC) ? bcnt_chunks[t * 256 + b] : 0;
    s[t] = v;
    __syncthreads();
    for (int off = 1; off < 256; off <<= 1) {
        int u = (t >= off) ? s[t - off] : 0;
        __syncthreads();
        s[t] += u;
        __syncthreads();
    }
    if (t < nbC) bcnt_chunks[t * 256 + b] = s[t] - v;   // exclusive within bucket
    if (t == 255) btot[b] = s[255];
}

// single tiny block: exclusive scan of 256 bucket totals -> bucket_base
__global__ __launch_bounds__(256) void bucket_base_scan(const int* __restrict__ btot,
                                                        int* __restrict__ bucket_base) {
    __shared__ int s[256];
    int t = threadIdx.x;
    int v = btot[t];
    s[t] = v;
    __syncthreads();
    for (int off = 1; off < 256; off <<= 1) {
        int u = (t >= off) ? s[t - off] : 0;
        __syncthreads();
        s[t] += u;
        __syncthreads();
    }
    bucket_base[t] = s[t] - v;
}

// Phase 1: coarse partition into col-buckets; run start = bucket_base + local prefix.
__global__ __launch_bounds__(256) void coarse_part(const int* __restrict__ row,
                                                   const int* __restrict__ col,
                                                   const int* __restrict__ run_local,
                                                   const int* __restrict__ bucket_base,
                                                   uint_t* __restrict__ ebuf, int E) {
    __shared__ uint_t stage[EPB];   // 16KB packed edges
    __shared__ int hist[256];
    __shared__ int hbase[256];
    int t = threadIdx.x;
    int e0 = blockIdx.x * EPB;
    int cnt = E - e0; if (cnt > EPB) cnt = EPB;
    hbase[t] = run_local[blockIdx.x * 256 + t] + bucket_base[t];
    hist[t] = 0;
    __syncthreads();
    for (int k = t; k < cnt; k += 256) {
        int c = col[e0 + k], r = row[e0 + k];
        stage[k] = ((uint_t)r << 16) | (uint_t)c;
    }
    __syncthreads();
    for (int k = t; k < cnt; k += 256) {
        uint_t p = stage[k];
        int b = (int)((p & 0xFFFFu) >> 8);
        int rk = atomicAdd(&hist[b], 1);   // local rank only (LDS)
        ebuf[hbase[b] + rk] = p;
    }
}

// Phase 2: per bucket build ptr/dinv + place erow (ushort rows).
__global__ __launch_bounds__(256) void fine_build(const int* __restrict__ bucket_base,
                                                  const uint_t* __restrict__ ebuf,
                                                  int* __restrict__ ptr,
                                                  float* __restrict__ dinv,
                                                  ushort_t* __restrict__ erow,
                                                  int N, int E, int nbuck) {
    __shared__ int hist[CPB];
    __shared__ int pref[CPB];
    int b = blockIdx.x;
    int cbase = b << 8;
    int t = threadIdx.x;
    int seg0 = bucket_base[b];
    int seg1 = (b + 1 < nbuck) ? bucket_base[b + 1] : E;
    hist[t] = 0;
    __syncthreads();
    for (int k = seg0 + t; k < seg1; k += 256)
        atomicAdd(&hist[ebuf[k] & 255u], 1);
    __syncthreads();
    int deg = hist[t];
    pref[t] = deg;
    __syncthreads();
    for (int off = 1; off < 256; off <<= 1) {
        int u = (t >= off) ? pref[t - off] : 0;
        __syncthreads();
        pref[t] += u;
        __syncthreads();
    }
    int base = seg0 + pref[t] - deg;
    int c = cbase + t;
    if (c < N) {
        ptr[c] = base;
        dinv[c] = rsqrtf((float)(deg + 1));
    }
    if (b == nbuck - 1 && t == 0) ptr[N] = E;
    __syncthreads();
    pref[t] = base;    // reuse as cursor
    __syncthreads();
    for (int k = seg0 + t; k < seg1; k += 256) {
        uint_t p = ebuf[k];
        int pos = atomicAdd(&pref[p & 255u], 1);
        erow[pos] = (ushort_t)(p >> 16);
    }
}

// ================= register-tiled GEMMs =================
__device__ __forceinline__ void fma4(float4& a, float xs, const float4& wv) {
    a.x = fmaf(xs, wv.x, a.x);
    a.y = fmaf(xs, wv.y, a.y);
    a.z = fmaf(xs, wv.z, a.z);
    a.w = fmaf(xs, wv.w, a.w);
}

// gemm1: xwb = (x @ W1) * dinv[row], stored bf16. tile 64x64, thread = 4x4.
__global__ __launch_bounds__(256) void gemm1(const float* __restrict__ x,
                                             const float* __restrict__ W,
                                             const float* __restrict__ dinv,
                                             ushort_t* __restrict__ xwb, int N) {
    __shared__ float Xl[64 * F0];   // 32KB, swizzled
    __shared__ float Wl[F0 * F1];   // 32KB, linear [k][64]
    int tid = threadIdx.x;
    int base = blockIdx.x * 64;

    const float4* W4 = (const float4*)W;
    float4* Wl4 = (float4*)Wl;
#pragma unroll
    for (int i = 0; i < 8; ++i) Wl4[tid + 256 * i] = W4[tid + 256 * i];

    float4* Xl4 = (float4*)Xl;
#pragma unroll
    for (int i = 0; i < 8; ++i) {
        int idx = tid + 256 * i;
        int r = idx >> 5, c4 = idx & 31;
        int gr = base + r;
        float4 v = (gr < N) ? ((const float4*)x)[(size_t)gr * 32 + c4]
                            : make_float4(0.f, 0.f, 0.f, 0.f);
        Xl4[r * 32 + (c4 ^ (r >> 2))] = v;
    }
    __syncthreads();

    int tc = tid & 15, tr = tid >> 4;
    float4 acc0 = make_float4(0.f, 0.f, 0.f, 0.f);
    float4 acc1 = acc0, acc2 = acc0, acc3 = acc0;
    const float4* Wl4c = (const float4*)Wl;
    const float4* Xl4c = (const float4*)Xl;

#pragma unroll 4
    for (int kk = 0; kk < 32; ++kk) {
        float4 xv0 = Xl4c[(4 * tr + 0) * 32 + (kk ^ tr)];
        float4 xv1 = Xl4c[(4 * tr + 1) * 32 + (kk ^ tr)];
        float4 xv2 = Xl4c[(4 * tr + 2) * 32 + (kk ^ tr)];
        float4 xv3 = Xl4c[(4 * tr + 3) * 32 + (kk ^ tr)];
        float4 w0 = Wl4c[(4 * kk + 0) * 16 + tc];
        float4 w1 = Wl4c[(4 * kk + 1) * 16 + tc];
        float4 w2 = Wl4c[(4 * kk + 2) * 16 + tc];
        float4 w3 = Wl4c[(4 * kk + 3) * 16 + tc];
        fma4(acc0, xv0.x, w0); fma4(acc0, xv0.y, w1); fma4(acc0, xv0.z, w2); fma4(acc0, xv0.w, w3);
        fma4(acc1, xv1.x, w0); fma4(acc1, xv1.y, w1); fma4(acc1, xv1.z, w2); fma4(acc1, xv1.w, w3);
        fma4(acc2, xv2.x, w0); fma4(acc2, xv2.y, w1); fma4(acc2, xv2.z, w2); fma4(acc2, xv2.w, w3);
        fma4(acc3, xv3.x, w0); fma4(acc3, xv3.y, w1); fma4(acc3, xv3.z, w2); fma4(acc3, xv3.w, w3);
    }

    int gr = base + 4 * tr;
#pragma unroll
    for (int k = 0; k < 4; ++k) {
        int r = gr + k;
        if (r < N) {
            float d = dinv[r];
            float4 a = (k == 0) ? acc0 : (k == 1) ? acc1 : (k == 2) ? acc2 : acc3;
            ushort4 o = make_ushort4(f2bf(a.x * d), f2bf(a.y * d), f2bf(a.z * d), f2bf(a.w * d));
            *(ushort4*)(&xwb[(size_t)r * F1 + 4 * tc]) = o;
        }
    }
}

// ================= layer 1 aggregation (r15 structure): wave/node, 2 edges/req
__global__ void agg1(const int* __restrict__ ptr, const ushort_t* __restrict__ erow,
                     const ushort_t* __restrict__ xwb, const float* __restrict__ dinv,
                     const float* __restrict__ b, ushort_t* __restrict__ h1b, int N) {
    int t = blockIdx.x * 256 + threadIdx.x;
    int i = t >> 6;
    if (i >= N) return;
    int l = t & 63, h = l >> 5, l2 = l & 31;
    const uint_t* xwb2 = (const uint_t*)xwb;

    float a0 = 0.f, a1 = 0.f;
    int e = ptr[i], end = ptr[i + 1];
    for (; e + 7 < end; e += 8) {
        int r0 = erow[e + 0 + h], r1 = erow[e + 2 + h];
        int r2 = erow[e + 4 + h], r3 = erow[e + 6 + h];
        uint_t v0 = xwb2[(size_t)r0 * 32 + l2];
        uint_t v1 = xwb2[(size_t)r1 * 32 + l2];
        uint_t v2 = xwb2[(size_t)r2 * 32 + l2];
        uint_t v3 = xwb2[(size_t)r3 * 32 + l2];
        a0 += bflo(v0); a1 += bfhi(v0);
        a0 += bflo(v1); a1 += bfhi(v1);
        a0 += bflo(v2); a1 += bfhi(v2);
        a0 += bflo(v3); a1 += bfhi(v3);
    }
    for (; e + 1 < end; e += 2) {
        int r0 = erow[e + h];
        uint_t v0 = xwb2[(size_t)r0 * 32 + l2];
        a0 += bflo(v0); a1 += bfhi(v0);
    }
    if (e < end && h == 0) {            // odd leftover: half 0 only
        uint_t v0 = xwb2[(size_t)erow[e] * 32 + l2];
        a0 += bflo(v0); a1 += bfhi(v0);
    }
    a0 += __shfl_down(a0, 32, 64);      // merge halves into lanes 0..31
    a1 += __shfl_down(a1, 32, 64);
    if (h == 0) {
        uint_t sv = xwb2[(size_t)i * 32 + l2];    // scaled self term
        a0 += bflo(sv); a1 += bfhi(sv);
        float d = dinv[i];
        float2 bb = ((const float2*)b)[l2];
        a0 = fmaxf(a0 * d + bb.x, 0.f);
        a1 = fmaxf(a1 * d + bb.y, 0.f);
        ((uint_t*)h1b)[(size_t)i * 32 + l2] = pack2(a0, a1);
    }
}

// gemm2: hwb = (h1b @ W2) * dinv[row], bf16 in / bf16 out. tile 128x32, 4x4.
__global__ __launch_bounds__(256) void gemm2(const ushort_t* __restrict__ h1b,
                                             const float* __restrict__ W,
                                             const float* __restrict__ dinv,
                                             ushort_t* __restrict__ hwb, int N) {
    __shared__ float Hl[128 * F1];  // 32KB, swizzled
    __shared__ float Wl[F1 * F2];   // 8KB
    int tid = threadIdx.x;
    int base = blockIdx.x * 128;

    const float4* W4 = (const float4*)W;
    float4* Wl4 = (float4*)Wl;
#pragma unroll
    for (int i = 0; i < 2; ++i) Wl4[tid + 256 * i] = W4[tid + 256 * i];

    const uint4* H4 = (const uint4*)h1b;
    float4* Hl4 = (float4*)Hl;
#pragma unroll
    for (int it = 0; it < 4; ++it) {
        int g = tid + 256 * it;
        int r = g >> 3, c8 = g & 7;
        int gr = base + r;
        uint4 v = (gr < N) ? H4[(size_t)gr * 8 + c8] : make_uint4(0, 0, 0, 0);
        float4 a, b2;
        a.x = bflo(v.x); a.y = bfhi(v.x);
        a.z = bflo(v.y); a.w = bfhi(v.y);
        b2.x = bflo(v.z); b2.y = bfhi(v.z);
        b2.z = bflo(v.w); b2.w = bfhi(v.w);
        int sw = (r >> 2) & 15;
        Hl4[r * 16 + ((2 * c8 + 0) ^ sw)] = a;
        Hl4[r * 16 + ((2 * c8 + 1) ^ sw)] = b2;
    }
    __syncthreads();

    int tc = tid & 7, tr = tid >> 3;
    float4 acc0 = make_float4(0.f, 0.f, 0.f, 0.f);
    float4 acc1 = acc0, acc2 = acc0, acc3 = acc0;
    const float4* Wl4c = (const float4*)Wl;
    const float4* Hl4c = (const float4*)Hl;

#pragma unroll 4
    for (int kk = 0; kk < 16; ++kk) {
        int sw = kk ^ (tr & 15);
        float4 xv0 = Hl4c[(4 * tr + 0) * 16 + sw];
        float4 xv1 = Hl4c[(4 * tr + 1) * 16 + sw];
        float4 xv2 = Hl4c[(4 * tr + 2) * 16 + sw];
        float4 xv3 = Hl4c[(4 * tr + 3) * 16 + sw];
        float4 w0 = Wl4c[(4 * kk + 0) * 8 + tc];
        float4 w1 = Wl4c[(4 * kk + 1) * 8 + tc];
        float4 w2 = Wl4c[(4 * kk + 2) * 8 + tc];
        float4 w3 = Wl4c[(4 * kk + 3) * 8 + tc];
        fma4(acc0, xv0.x, w0); fma4(acc0, xv0.y, w1); fma4(acc0, xv0.z, w2); fma4(acc0, xv0.w, w3);
        fma4(acc1, xv1.x, w0); fma4(acc1, xv1.y, w1); fma4(acc1, xv1.z, w2); fma4(acc1, xv1.w, w3);
        fma4(acc2, xv2.x, w0); fma4(acc2, xv2.y, w1); fma4(acc2, xv2.z, w2); fma4(acc2, xv2.w, w3);
        fma4(acc3, xv3.x, w0); fma4(acc3, xv3.y, w1); fma4(acc3, xv3.z, w2); fma4(acc3, xv3.w, w3);
    }

    int gr = base + 4 * tr;
#pragma unroll
    for (int k = 0; k < 4; ++k) {
        int r = gr + k;
        if (r < N) {
            float d = dinv[r];
            float4 a = (k == 0) ? acc0 : (k == 1) ? acc1 : (k == 2) ? acc2 : acc3;
            ushort4 o = make_ushort4(f2bf(a.x * d), f2bf(a.y * d), f2bf(a.z * d), f2bf(a.w * d));
            *(ushort4*)(&hwb[(size_t)r * F2 + 4 * tc]) = o;
        }
    }
}

// ================= layer 2 aggregation + fused log_softmax (r15 structure) ====
__global__ void agg2_lsm(const int* __restrict__ ptr, const ushort_t* __restrict__ erow,
                         const ushort_t* __restrict__ hwb, const float* __restrict__ dinv,
                         const float* __restrict__ b, float* __restrict__ out, int N) {
    int t = blockIdx.x * 256 + threadIdx.x;
    int i = t >> 5;
    if (i >= N) return;
    int g = t & 31, h = g >> 4, l2 = g & 15;
    const uint_t* hwb2 = (const uint_t*)hwb;

    float a0 = 0.f, a1 = 0.f;
    int e = ptr[i], end = ptr[i + 1];
    for (; e + 7 < end; e += 8) {
        int r0 = erow[e + 0 + h], r1 = erow[e + 2 + h];
        int r2 = erow[e + 4 + h], r3 = erow[e + 6 + h];
        uint_t v0 = hwb2[(size_t)r0 * 16 + l2];
        uint_t v1 = hwb2[(size_t)r1 * 16 + l2];
        uint_t v2 = hwb2[(size_t)r2 * 16 + l2];
        uint_t v3 = hwb2[(size_t)r3 * 16 + l2];
        a0 += bflo(v0); a1 += bfhi(v0);
        a0 += bflo(v1); a1 += bfhi(v1);
        a0 += bflo(v2); a1 += bfhi(v2);
        a0 += bflo(v3); a1 += bfhi(v3);
    }
    for (; e + 1 < end; e += 2) {
        int r0 = erow[e + h];
        uint_t v0 = hwb2[(size_t)r0 * 16 + l2];
        a0 += bflo(v0); a1 += bfhi(v0);
    }
    if (e < end && h == 0) {
        uint_t v0 = hwb2[(size_t)erow[e] * 16 + l2];
        a0 += bflo(v0); a1 += bfhi(v0);
    }
    a0 += __shfl_down(a0, 16, 32);     // merge slots into lanes (g<16)
    a1 += __shfl_down(a1, 16, 32);

    uint_t sv = hwb2[(size_t)i * 16 + l2];
    a0 += bflo(sv); a1 += bfhi(sv);
    float d = dinv[i];
    float2 bb = ((const float2*)b)[l2];
    a0 = a0 * d + bb.x;
    a1 = a1 * d + bb.y;

    float m = fmaxf(a0, a1);
    for (int off = 8; off; off >>= 1) m = fmaxf(m, __shfl_xor(m, off, 16));
    float s = expf(a0 - m) + expf(a1 - m);
    for (int off = 8; off; off >>= 1) s += __shfl_xor(s, off, 16);
    float ls = logf(s);
    if (h == 0)
        ((float2*)out)[(size_t)i * 16 + l2] = make_float2(a0 - m - ls, a1 - m - ls);
}

extern "C" void kernel_launch(void* const* d_in, const int* in_sizes, int n_in,
                              void* d_out, int out_size, void* d_ws, size_t ws_size,
                              hipStream_t stream) {
    const float* x  = (const float*)d_in[0];
    const int*   ei = (const int*)d_in[1];
    const float* W1 = (const float*)d_in[2];
    const float* b1 = (const float*)d_in[3];
    const float* W2 = (const float*)d_in[4];
    const float* b2 = (const float*)d_in[5];

    int N = in_sizes[0] / F0;
    int E = in_sizes[1] / 2;
    const int* row = ei;
    const int* col = ei + E;

    int nbC   = (E + EPB - 1) / EPB;          // edge chunks (<= 256)
    int nbuck = (N + CPB - 1) / CPB;          // buckets

    size_t Np = ((size_t)N + 63) & ~(size_t)63;
    size_t Ep = ((size_t)E + 63) & ~(size_t)63;
    size_t Cp = (((size_t)nbC * 256) + 63) & ~(size_t)63;
    int*      bcnt_chunks = (int*)d_ws;                  // nbC*256 (counts -> local prefixes)
    int*      btot        = bcnt_chunks + Cp;            // 256
    int*      bucket_base = btot + 256;                  // 256
    int*      ptr         = bucket_base + 256 + 64;      // Np+64
    float*    dinv        = (float*)(ptr + Np + 64);     // Np
    ushort_t* erow        = (ushort_t*)(dinv + Np);      // Ep ushorts
    uint_t*   ebuf        = (uint_t*)(erow + Ep);        // Ep packed edges
    ushort_t* xwb         = (ushort_t*)(ebuf + Ep);      // Np*64 bf16
    ushort_t* h1b         = xwb + Np * F1;               // Np*64 bf16
    ushort_t* hwb         = h1b + Np * F1;               // Np*32 bf16
    float*    out2        = (float*)d_out;

    bucket_count<<<nbC, 256, 0, stream>>>(col, bcnt_chunks, E);
    per_bucket_scan<<<256, 256, 0, stream>>>(bcnt_chunks, nbC, btot);
    bucket_base_scan<<<1, 256, 0, stream>>>(btot, bucket_base);
    coarse_part<<<nbC, 256, 0, stream>>>(row, col, bcnt_chunks, bucket_base, ebuf, E);
    fine_build<<<nbuck, 256, 0, stream>>>(bucket_base, ebuf, ptr, dinv, erow, N, E, nbuck);

    gemm1<<<(N + 63) / 64, 256, 0, stream>>>(x, W1, dinv, xwb, N);
    agg1<<<(int)(((size_t)N * 64 + 255) / 256), 256, 0, stream>>>(ptr, erow, xwb, dinv, b1, h1b, N);
    gemm2<<<(N + 127) / 128, 256, 0, stream>>>(h1b, W2, dinv, hwb, N);
    agg2_lsm<<<(int)(((size_t)N * 32 + 255) / 256), 256, 0, stream>>>(ptr, erow, hwb, dinv, b2, out2, N);
}

// Round 22
// 110.083 us; speedup vs baseline: 1.9258x; 1.0105x over previous
//
#include <hip/hip_runtime.h>

#define F0 128
#define F1 64
#define F2 32
#define CPB 256    // cols per bucket (bucket = col >> 8; requires N < 65536)
#define EPB 4096   // edges per coarse block (nbC = ceil(E/EPB) must be <= 256)

typedef unsigned short ushort_t;
typedef unsigned int uint_t;

__device__ __forceinline__ ushort_t f2bf(float f) {   // f32 -> bf16 RNE
    uint_t u = __float_as_uint(f);
    return (ushort_t)((u + 0x7FFFu + ((u >> 16) & 1u)) >> 16);
}
__device__ __forceinline__ float bflo(uint_t v) { return __uint_as_float(v << 16); }
__device__ __forceinline__ float bfhi(uint_t v) { return __uint_as_float(v & 0xFFFF0000u); }
__device__ __forceinline__ uint_t pack2(float a, float b) {
    return (uint_t)f2bf(a) | ((uint_t)f2bf(b) << 16);
}

// ================= CSR build (bucket-level front-end) =================
// per-chunk bucket counts, written non-atomically (no zeroing pass needed)
__global__ __launch_bounds__(256) void bucket_count(const int* __restrict__ col,
                                                    int* __restrict__ bcnt_chunks, int E) {
    __shared__ int h[256];
    int t = threadIdx.x;
    h[t] = 0;
    __syncthreads();
    int e0 = blockIdx.x * EPB;
    int cnt = E - e0; if (cnt > EPB) cnt = EPB;
    for (int k = t; k < cnt; k += 256) atomicAdd(&h[col[e0 + k] >> 8], 1);
    __syncthreads();
    bcnt_chunks[blockIdx.x * 256 + t] = h[t];
}

// 256 blocks, one per bucket b: parallel scan of h[c][b] over chunks c.
// Rewrites bcnt_chunks[c][b] as the within-bucket exclusive prefix; btot[b]=total.
__global__ __launch_bounds__(256) void per_bucket_scan(int* __restrict__ bcnt_chunks,
                                                       int nbC, int* __restrict__ btot) {
    __shared__ int s[256];
    int b = blockIdx.x;
    int t = threadIdx.x;
    int v = (t < nbC) ? bcnt_chunks[t * 256 + b] : 0;
    s[t] = v;
    __syncthreads();
    for (int off = 1; off < 256; off <<= 1) {
        int u = (t >= off) ? s[t - off] : 0;
        __syncthreads();
        s[t] += u;
        __syncthreads();
    }
    if (t < nbC) bcnt_chunks[t * 256 + b] = s[t] - v;   // exclusive within bucket
    if (t == 255) btot[b] = s[255];
}

// Phase 1: coarse partition; bucket_base recomputed locally from btot.
__global__ __launch_bounds__(256) void coarse_part(const int* __restrict__ row,
                                                   const int* __restrict__ col,
                                                   const int* __restrict__ run_local,
                                                   const int* __restrict__ btot,
                                                   uint_t* __restrict__ ebuf, int E) {
    __shared__ uint_t stage[EPB];   // 16KB packed edges
    __shared__ int hist[256];
    __shared__ int hbase[256];
    __shared__ int sb[256];
    int t = threadIdx.x;
    int e0 = blockIdx.x * EPB;
    int cnt = E - e0; if (cnt > EPB) cnt = EPB;

    int bv = btot[t];
    sb[t] = bv;
    __syncthreads();
    for (int off = 1; off < 256; off <<= 1) {
        int u = (t >= off) ? sb[t - off] : 0;
        __syncthreads();
        sb[t] += u;
        __syncthreads();
    }
    hbase[t] = run_local[blockIdx.x * 256 + t] + (sb[t] - bv);  // global run start
    hist[t] = 0;
    __syncthreads();
    for (int k = t; k < cnt; k += 256) {
        int c = col[e0 + k], r = row[e0 + k];
        stage[k] = ((uint_t)r << 16) | (uint_t)c;
    }
    __syncthreads();
    for (int k = t; k < cnt; k += 256) {
        uint_t p = stage[k];
        int b = (int)((p & 0xFFFFu) >> 8);
        int rk = atomicAdd(&hist[b], 1);   // local rank only (LDS)
        ebuf[hbase[b] + rk] = p;
    }
}

// Phase 2: per bucket build ptr/dinv + place erow; bucket_base recomputed locally.
__global__ __launch_bounds__(256) void fine_build(const int* __restrict__ btot,
                                                  const uint_t* __restrict__ ebuf,
                                                  int* __restrict__ ptr,
                                                  float* __restrict__ dinv,
                                                  ushort_t* __restrict__ erow,
                                                  int N, int E, int nbuck) {
    __shared__ int hist[CPB];
    __shared__ int pref[CPB];
    __shared__ int seg_sh[2];
    int b = blockIdx.x;
    int cbase = b << 8;
    int t = threadIdx.x;

    int bv = btot[t];
    pref[t] = bv;
    __syncthreads();
    for (int off = 1; off < 256; off <<= 1) {
        int u = (t >= off) ? pref[t - off] : 0;
        __syncthreads();
        pref[t] += u;
        __syncthreads();
    }
    int excl = pref[t] - bv;
    if (t == b) seg_sh[0] = excl;
    if (b < 255 && t == b + 1) seg_sh[1] = excl;
    if (b == 255 && t == 0) seg_sh[1] = E;
    hist[t] = 0;
    __syncthreads();
    int seg0 = seg_sh[0];
    int seg1 = seg_sh[1];

    for (int k = seg0 + t; k < seg1; k += 256)
        atomicAdd(&hist[ebuf[k] & 255u], 1);
    __syncthreads();
    int deg = hist[t];
    pref[t] = deg;
    __syncthreads();
    for (int off = 1; off < 256; off <<= 1) {
        int u = (t >= off) ? pref[t - off] : 0;
        __syncthreads();
        pref[t] += u;
        __syncthreads();
    }
    int base = seg0 + pref[t] - deg;
    int c = cbase + t;
    if (c < N) {
        ptr[c] = base;
        dinv[c] = rsqrtf((float)(deg + 1));
    }
    if (b == nbuck - 1 && t == 0) ptr[N] = E;
    __syncthreads();
    pref[t] = base;    // reuse as cursor
    __syncthreads();
    for (int k = seg0 + t; k < seg1; k += 256) {
        uint_t p = ebuf[k];
        int pos = atomicAdd(&pref[p & 255u], 1);
        erow[pos] = (ushort_t)(p >> 16);
    }
}

// ================= register-tiled GEMMs =================
__device__ __forceinline__ void fma4(float4& a, float xs, const float4& wv) {
    a.x = fmaf(xs, wv.x, a.x);
    a.y = fmaf(xs, wv.y, a.y);
    a.z = fmaf(xs, wv.z, a.z);
    a.w = fmaf(xs, wv.w, a.w);
}

// gemm1: xwb = (x @ W1) * dinv[row], stored bf16. tile 64x64, thread = 4x4.
__global__ __launch_bounds__(256) void gemm1(const float* __restrict__ x,
                                             const float* __restrict__ W,
                                             const float* __restrict__ dinv,
                                             ushort_t* __restrict__ xwb, int N) {
    __shared__ float Xl[64 * F0];   // 32KB, swizzled
    __shared__ float Wl[F0 * F1];   // 32KB, linear [k][64]
    int tid = threadIdx.x;
    int base = blockIdx.x * 64;

    const float4* W4 = (const float4*)W;
    float4* Wl4 = (float4*)Wl;
#pragma unroll
    for (int i = 0; i < 8; ++i) Wl4[tid + 256 * i] = W4[tid + 256 * i];

    float4* Xl4 = (float4*)Xl;
#pragma unroll
    for (int i = 0; i < 8; ++i) {
        int idx = tid + 256 * i;
        int r = idx >> 5, c4 = idx & 31;
        int gr = base + r;
        float4 v = (gr < N) ? ((const float4*)x)[(size_t)gr * 32 + c4]
                            : make_float4(0.f, 0.f, 0.f, 0.f);
        Xl4[r * 32 + (c4 ^ (r >> 2))] = v;
    }
    __syncthreads();

    int tc = tid & 15, tr = tid >> 4;
    float4 acc0 = make_float4(0.f, 0.f, 0.f, 0.f);
    float4 acc1 = acc0, acc2 = acc0, acc3 = acc0;
    const float4* Wl4c = (const float4*)Wl;
    const float4* Xl4c = (const float4*)Xl;

#pragma unroll 4
    for (int kk = 0; kk < 32; ++kk) {
        float4 xv0 = Xl4c[(4 * tr + 0) * 32 + (kk ^ tr)];
        float4 xv1 = Xl4c[(4 * tr + 1) * 32 + (kk ^ tr)];
        float4 xv2 = Xl4c[(4 * tr + 2) * 32 + (kk ^ tr)];
        float4 xv3 = Xl4c[(4 * tr + 3) * 32 + (kk ^ tr)];
        float4 w0 = Wl4c[(4 * kk + 0) * 16 + tc];
        float4 w1 = Wl4c[(4 * kk + 1) * 16 + tc];
        float4 w2 = Wl4c[(4 * kk + 2) * 16 + tc];
        float4 w3 = Wl4c[(4 * kk + 3) * 16 + tc];
        fma4(acc0, xv0.x, w0); fma4(acc0, xv0.y, w1); fma4(acc0, xv0.z, w2); fma4(acc0, xv0.w, w3);
        fma4(acc1, xv1.x, w0); fma4(acc1, xv1.y, w1); fma4(acc1, xv1.z, w2); fma4(acc1, xv1.w, w3);
        fma4(acc2, xv2.x, w0); fma4(acc2, xv2.y, w1); fma4(acc2, xv2.z, w2); fma4(acc2, xv2.w, w3);
        fma4(acc3, xv3.x, w0); fma4(acc3, xv3.y, w1); fma4(acc3, xv3.z, w2); fma4(acc3, xv3.w, w3);
    }

    int gr = base + 4 * tr;
#pragma unroll
    for (int k = 0; k < 4; ++k) {
        int r = gr + k;
        if (r < N) {
            float d = dinv[r];
            float4 a = (k == 0) ? acc0 : (k == 1) ? acc1 : (k == 2) ? acc2 : acc3;
            ushort4 o = make_ushort4(f2bf(a.x * d), f2bf(a.y * d), f2bf(a.z * d), f2bf(a.w * d));
            *(ushort4*)(&xwb[(size_t)r * F1 + 4 * tc]) = o;
        }
    }
}

// ================= layer 1 aggregation (r15 structure): wave/node, 2 edges/req
__global__ void agg1(const int* __restrict__ ptr, const ushort_t* __restrict__ erow,
                     const ushort_t* __restrict__ xwb, const float* __restrict__ dinv,
                     const float* __restrict__ b, ushort_t* __restrict__ h1b, int N) {
    int t = blockIdx.x * 256 + threadIdx.x;
    int i = t >> 6;
    if (i >= N) return;
    int l = t & 63, h = l >> 5, l2 = l & 31;
    const uint_t* xwb2 = (const uint_t*)xwb;

    float a0 = 0.f, a1 = 0.f;
    int e = ptr[i], end = ptr[i + 1];
    for (; e + 7 < end; e += 8) {
        int r0 = erow[e + 0 + h], r1 = erow[e + 2 + h];
        int r2 = erow[e + 4 + h], r3 = erow[e + 6 + h];
        uint_t v0 = xwb2[(size_t)r0 * 32 + l2];
        uint_t v1 = xwb2[(size_t)r1 * 32 + l2];
        uint_t v2 = xwb2[(size_t)r2 * 32 + l2];
        uint_t v3 = xwb2[(size_t)r3 * 32 + l2];
        a0 += bflo(v0); a1 += bfhi(v0);
        a0 += bflo(v1); a1 += bfhi(v1);
        a0 += bflo(v2); a1 += bfhi(v2);
        a0 += bflo(v3); a1 += bfhi(v3);
    }
    for (; e + 1 < end; e += 2) {
        int r0 = erow[e + h];
        uint_t v0 = xwb2[(size_t)r0 * 32 + l2];
        a0 += bflo(v0); a1 += bfhi(v0);
    }
    if (e < end && h == 0) {            // odd leftover: half 0 only
        uint_t v0 = xwb2[(size_t)erow[e] * 32 + l2];
        a0 += bflo(v0); a1 += bfhi(v0);
    }
    a0 += __shfl_down(a0, 32, 64);      // merge halves into lanes 0..31
    a1 += __shfl_down(a1, 32, 64);
    if (h == 0) {
        uint_t sv = xwb2[(size_t)i * 32 + l2];    // scaled self term
        a0 += bflo(sv); a1 += bfhi(sv);
        float d = dinv[i];
        float2 bb = ((const float2*)b)[l2];
        a0 = fmaxf(a0 * d + bb.x, 0.f);
        a1 = fmaxf(a1 * d + bb.y, 0.f);
        ((uint_t*)h1b)[(size_t)i * 32 + l2] = pack2(a0, a1);
    }
}

// gemm2: hwb = (h1b @ W2) * dinv[row], bf16 in / bf16 out. tile 128x32, 4x4.
__global__ __launch_bounds__(256) void gemm2(const ushort_t* __restrict__ h1b,
                                             const float* __restrict__ W,
                                             const float* __restrict__ dinv,
                                             ushort_t* __restrict__ hwb, int N) {
    __shared__ float Hl[128 * F1];  // 32KB, swizzled
    __shared__ float Wl[F1 * F2];   // 8KB
    int tid = threadIdx.x;
    int base = blockIdx.x * 128;

    const float4* W4 = (const float4*)W;
    float4* Wl4 = (float4*)Wl;
#pragma unroll
    for (int i = 0; i < 2; ++i) Wl4[tid + 256 * i] = W4[tid + 256 * i];

    const uint4* H4 = (const uint4*)h1b;
    float4* Hl4 = (float4*)Hl;
#pragma unroll
    for (int it = 0; it < 4; ++it) {
        int g = tid + 256 * it;
        int r = g >> 3, c8 = g & 7;
        int gr = base + r;
        uint4 v = (gr < N) ? H4[(size_t)gr * 8 + c8] : make_uint4(0, 0, 0, 0);
        float4 a, b2;
        a.x = bflo(v.x); a.y = bfhi(v.x);
        a.z = bflo(v.y); a.w = bfhi(v.y);
        b2.x = bflo(v.z); b2.y = bfhi(v.z);
        b2.z = bflo(v.w); b2.w = bfhi(v.w);
        int sw = (r >> 2) & 15;
        Hl4[r * 16 + ((2 * c8 + 0) ^ sw)] = a;
        Hl4[r * 16 + ((2 * c8 + 1) ^ sw)] = b2;
    }
    __syncthreads();

    int tc = tid & 7, tr = tid >> 3;
    float4 acc0 = make_float4(0.f, 0.f, 0.f, 0.f);
    float4 acc1 = acc0, acc2 = acc0, acc3 = acc0;
    const float4* Wl4c = (const float4*)Wl;
    const float4* Hl4c = (const float4*)Hl;

#pragma unroll 4
    for (int kk = 0; kk < 16; ++kk) {
        int sw = kk ^ (tr & 15);
        float4 xv0 = Hl4c[(4 * tr + 0) * 16 + sw];
        float4 xv1 = Hl4c[(4 * tr + 1) * 16 + sw];
        float4 xv2 = Hl4c[(4 * tr + 2) * 16 + sw];
        float4 xv3 = Hl4c[(4 * tr + 3) * 16 + sw];
        float4 w0 = Wl4c[(4 * kk + 0) * 8 + tc];
        float4 w1 = Wl4c[(4 * kk + 1) * 8 + tc];
        float4 w2 = Wl4c[(4 * kk + 2) * 8 + tc];
        float4 w3 = Wl4c[(4 * kk + 3) * 8 + tc];
        fma4(acc0, xv0.x, w0); fma4(acc0, xv0.y, w1); fma4(acc0, xv0.z, w2); fma4(acc0, xv0.w, w3);
        fma4(acc1, xv1.x, w0); fma4(acc1, xv1.y, w1); fma4(acc1, xv1.z, w2); fma4(acc1, xv1.w, w3);
        fma4(acc2, xv2.x, w0); fma4(acc2, xv2.y, w1); fma4(acc2, xv2.z, w2); fma4(acc2, xv2.w, w3);
        fma4(acc3, xv3.x, w0); fma4(acc3, xv3.y, w1); fma4(acc3, xv3.z, w2); fma4(acc3, xv3.w, w3);
    }

    int gr = base + 4 * tr;
#pragma unroll
    for (int k = 0; k < 4; ++k) {
        int r = gr + k;
        if (r < N) {
            float d = dinv[r];
            float4 a = (k == 0) ? acc0 : (k == 1) ? acc1 : (k == 2) ? acc2 : acc3;
            ushort4 o = make_ushort4(f2bf(a.x * d), f2bf(a.y * d), f2bf(a.z * d), f2bf(a.w * d));
            *(ushort4*)(&hwb[(size_t)r * F2 + 4 * tc]) = o;
        }
    }
}

// ================= layer 2 aggregation + fused log_softmax (r15 structure) ====
__global__ void agg2_lsm(const int* __restrict__ ptr, const ushort_t* __restrict__ erow,
                         const ushort_t* __restrict__ hwb, const float* __restrict__ dinv,
                         const float* __restrict__ b, float* __restrict__ out, int N) {
    int t = blockIdx.x * 256 + threadIdx.x;
    int i = t >> 5;
    if (i >= N) return;
    int g = t & 31, h = g >> 4, l2 = g & 15;
    const uint_t* hwb2 = (const uint_t*)hwb;

    float a0 = 0.f, a1 = 0.f;
    int e = ptr[i], end = ptr[i + 1];
    for (; e + 7 < end; e += 8) {
        int r0 = erow[e + 0 + h], r1 = erow[e + 2 + h];
        int r2 = erow[e + 4 + h], r3 = erow[e + 6 + h];
        uint_t v0 = hwb2[(size_t)r0 * 16 + l2];
        uint_t v1 = hwb2[(size_t)r1 * 16 + l2];
        uint_t v2 = hwb2[(size_t)r2 * 16 + l2];
        uint_t v3 = hwb2[(size_t)r3 * 16 + l2];
        a0 += bflo(v0); a1 += bfhi(v0);
        a0 += bflo(v1); a1 += bfhi(v1);
        a0 += bflo(v2); a1 += bfhi(v2);
        a0 += bflo(v3); a1 += bfhi(v3);
    }
    for (; e + 1 < end; e += 2) {
        int r0 = erow[e + h];
        uint_t v0 = hwb2[(size_t)r0 * 16 + l2];
        a0 += bflo(v0); a1 += bfhi(v0);
    }
    if (e < end && h == 0) {
        uint_t v0 = hwb2[(size_t)erow[e] * 16 + l2];
        a0 += bflo(v0); a1 += bfhi(v0);
    }
    a0 += __shfl_down(a0, 16, 32);     // merge slots into lanes (g<16)
    a1 += __shfl_down(a1, 16, 32);

    uint_t sv = hwb2[(size_t)i * 16 + l2];
    a0 += bflo(sv); a1 += bfhi(sv);
    float d = dinv[i];
    float2 bb = ((const float2*)b)[l2];
    a0 = a0 * d + bb.x;
    a1 = a1 * d + bb.y;

    float m = fmaxf(a0, a1);
    for (int off = 8; off; off >>= 1) m = fmaxf(m, __shfl_xor(m, off, 16));
    float s = expf(a0 - m) + expf(a1 - m);
    for (int off = 8; off; off >>= 1) s += __shfl_xor(s, off, 16);
    float ls = logf(s);
    if (h == 0)
        ((float2*)out)[(size_t)i * 16 + l2] = make_float2(a0 - m - ls, a1 - m - ls);
}

extern "C" void kernel_launch(void* const* d_in, const int* in_sizes, int n_in,
                              void* d_out, int out_size, void* d_ws, size_t ws_size,
                              hipStream_t stream) {
    const float* x  = (const float*)d_in[0];
    const int*   ei = (const int*)d_in[1];
    const float* W1 = (const float*)d_in[2];
    const float* b1 = (const float*)d_in[3];
    const float* W2 = (const float*)d_in[4];
    const float* b2 = (const float*)d_in[5];

    int N = in_sizes[0] / F0;
    int E = in_sizes[1] / 2;
    const int* row = ei;
    const int* col = ei + E;

    int nbC   = (E + EPB - 1) / EPB;          // edge chunks (<= 256)
    int nbuck = (N + CPB - 1) / CPB;          // buckets

    size_t Np = ((size_t)N + 63) & ~(size_t)63;
    size_t Ep = ((size_t)E + 63) & ~(size_t)63;
    size_t Cp = (((size_t)nbC * 256) + 63) & ~(size_t)63;
    int*      bcnt_chunks = (int*)d_ws;                  // nbC*256 (counts -> local prefixes)
    int*      btot        = bcnt_chunks + Cp;            // 256
    int*      ptr         = btot + 256 + 64;             // Np+64
    float*    dinv        = (float*)(ptr + Np + 64);     // Np
    ushort_t* erow        = (ushort_t*)(dinv + Np);      // Ep ushorts
    uint_t*   ebuf        = (uint_t*)(erow + Ep);        // Ep packed edges
    ushort_t* xwb         = (ushort_t*)(ebuf + Ep);      // Np*64 bf16
    ushort_t* h1b         = xwb + Np * F1;               // Np*64 bf16
    ushort_t* hwb         = h1b + Np * F1;               // Np*32 bf16
    float*    out2        = (float*)d_out;

    bucket_count<<<nbC, 256, 0, stream>>>(col, bcnt_chunks, E);
    per_bucket_scan<<<256, 256, 0, stream>>>(bcnt_chunks, nbC, btot);
    coarse_part<<<nbC, 256, 0, stream>>>(row, col, bcnt_chunks, btot, ebuf, E);
    fine_build<<<nbuck, 256, 0, stream>>>(btot, ebuf, ptr, dinv, erow, N, E, nbuck);

    gemm1<<<(N + 63) / 64, 256, 0, stream>>>(x, W1, dinv, xwb, N);
    agg1<<<(int)(((size_t)N * 64 + 255) / 256), 256, 0, stream>>>(ptr, erow, xwb, dinv, b1, h1b, N);
    gemm2<<<(N + 127) / 128, 256, 0, stream>>>(h1b, W2, dinv, hwb, N);
    agg2_lsm<<<(int)(((size_t)N * 32 + 255) / 256), 256, 0, stream>>>(ptr, erow, hwb, dinv, b2, out2, N);
}